// Round 14
// baseline (304.057 us; speedup 1.0000x reference)
//
#include <hip/hip_runtime.h>
#include <math.h>

#define N0c   16
#define NAt   96
#define ORIG  92
#define Fc    64
#define Kc    41
#define Hc    128
#define NCc   3
#define C2    128   // 2F
#define EPSBN 1e-5f
#define JG    4
#define JPW   (NAt / JG)
#define NREP  32    // atomic replica slots
#define SRL_STRIDE 12288   // per-layer replica block
#define AROW  72    // k_apply LDS A row stride (ushorts)
#define WFRAG 16384 // ushorts per layer in W3F (k_apply B frags)
#define PROW  200   // k_pgemm LDS A row stride (ushorts): 192 + 8 pad
#define DROW  516   // k_pgemm LDS D row stride (floats): 512 + 4 pad
#define PGFRAG (32 * 2 * 2 * 512)  // ushorts per layer in W3F2 (pgemm B frags)
#define INV1  (1.f / (float)(N0c * NAt * NAt))
#define INV2  (1.f / (float)(N0c * NAt))

typedef __attribute__((ext_vector_type(8))) short short8_t;   // 8 bf16
typedef __attribute__((ext_vector_type(4))) float f32x4;

__device__ __forceinline__ float sp_(float x){
    return fmaxf(x, 0.f) + __logf(1.f + __expf(-fabsf(x)));
}
__device__ __forceinline__ float sgm_(float x){
    return 1.f / (1.f + __expf(-x));
}
__device__ __forceinline__ unsigned short bfhi(float x){
    union { float f; unsigned u; } v; v.f = x;
    unsigned r = v.u + 0x7fff + ((v.u >> 16) & 1);   // RNE to bf16
    return (unsigned short)(r >> 16);
}
__device__ __forceinline__ float bf2f(unsigned short h){
    union { float f; unsigned u; } v; v.u = ((unsigned)h) << 16; return v.f;
}

// fea = atom @ emb_W + emb_b
__global__ __launch_bounds__(256) void k_embed(const float* __restrict__ atom,
                                               const float* __restrict__ W,
                                               const float* __restrict__ b,
                                               float* __restrict__ fea){
    int row = blockIdx.x * 4 + (threadIdx.x >> 6);
    int f   = threadIdx.x & 63;
    const float* ar = atom + row * ORIG;
    float acc = b[f];
    #pragma unroll 4
    for (int o = 0; o < ORIG; ++o) acc += ar[o] * W[o * Fc + f];
    fea[row * Fc + f] = acc;
}

// One-time: S_r, T_r, cnt_r.
__global__ __launch_bounds__(256) void k_pre(const float* __restrict__ nbr,
                                             const int*   __restrict__ adj,
                                             float* __restrict__ ST,
                                             float* __restrict__ cntf){
    int r    = blockIdx.x;
    int lane = threadIdx.x & 63;
    int jg   = __builtin_amdgcn_readfirstlane(threadIdx.x >> 6);
    __shared__ float rS[JG][Kc], rT[JG][Kc], rc[JG];
    float S = 0.f, T = 0.f, cn = 0.f;
    int j0 = jg * JPW;
    for (int j = j0; j < j0 + JPW; ++j){
        float a = (float)adj[r * NAt + j];
        float v = (lane < Kc) ? nbr[((size_t)r * NAt + j) * Kc + lane] : 0.f;
        S += v; T += a * v; cn += a;
    }
    if (lane < Kc){ rS[jg][lane] = S; rT[jg][lane] = T; }
    if (lane == 0) rc[jg] = cn;
    __syncthreads();
    int t = threadIdx.x;
    if (t < Kc){
        ST[r * (2 * Kc) + t]      = rS[0][t] + rS[1][t] + rS[2][t] + rS[3][t];
        ST[r * (2 * Kc) + Kc + t] = rT[0][t] + rT[1][t] + rT[2][t] + rT[3][t];
    }
    if (t == 0) cntf[r] = rc[0] + rc[1] + rc[2] + rc[3];
}

// Gram partials (identical to R13).
__global__ __launch_bounds__(128) void k_gram(const float* __restrict__ nbr,
                                              float* __restrict__ pG, int rpb){
    int blk = blockIdx.x;
    int t   = threadIdx.x;
    int k   = (t % 21) * 2;
    int lb  = (t / 21) * 7;
    __shared__ float L[NAt * Kc];
    float a0[7] = {0,0,0,0,0,0,0}, a1[7] = {0,0,0,0,0,0,0};
    for (int rr = 0; rr < rpb; ++rr){
        int r = blk * rpb + rr;
        __syncthreads();
        for (int i = t; i < NAt * Kc; i += 128)
            L[i] = nbr[(size_t)r * NAt * Kc + i];
        __syncthreads();
        if (t < 126){
            for (int j = 0; j < NAt; ++j){
                float vk0 = L[j * Kc + k];
                float vk1 = (k + 1 < Kc) ? L[j * Kc + k + 1] : 0.f;
                #pragma unroll
                for (int m = 0; m < 7; ++m){
                    if (lb + m < Kc){
                        float lv = L[j * Kc + lb + m];
                        a0[m] += vk0 * lv;
                        a1[m] += vk1 * lv;
                    }
                }
            }
        }
    }
    if (t < 126){
        float* dst = pG + (size_t)blk * (Kc * Kc);
        #pragma unroll
        for (int m = 0; m < 7; ++m){
            if (lb + m < Kc){
                dst[k * Kc + lb + m] = a0[m];
                if (k + 1 < Kc) dst[(k + 1) * Kc + lb + m] = a1[m];
            }
        }
    }
}

__global__ __launch_bounds__(64) void k_gred(const float* __restrict__ pG,
                                             float* __restrict__ G){
    int i  = (blockIdx.x % 27) * 64 + threadIdx.x;
    int b0 = (blockIdx.x / 27) * 96;
    if (i < Kc * Kc){
        float s = 0.f;
        #pragma unroll 4
        for (int b = b0; b < b0 + 96; ++b) s += pG[(size_t)b * (Kc * Kc) + i];
        atomicAdd(&G[i], s);
    }
}

// One-time: k_apply B-fragments (identical to R13, verified).
__global__ __launch_bounds__(256) void k_wtb(const float* __restrict__ convW,
                                             unsigned short* __restrict__ W3F){
    int l = blockIdx.x;
    const float* Wl = convW + (size_t)l * 169 * C2;
    for (int it = 0; it < 8; ++it){
        int idx  = threadIdx.x + it * 256;
        int lane = idx & 63;
        int fid  = idx >> 6;
        int h    = fid & 1;
        int ks   = (fid >> 1) & 1;
        int nt   = fid >> 2;
        int n    = nt * 16 + (lane & 15);
        unsigned short* dst = W3F + (size_t)l * WFRAG + fid * 512 + lane * 8;
        #pragma unroll
        for (int i = 0; i < 8; ++i){
            int k = ks * 32 + (lane >> 4) * 8 + i;
            float w = (k < Kc) ? Wl[(C2 + k) * C2 + n] : 0.f;
            unsigned short hi = bfhi(w);
            dst[i] = h ? bfhi(w - bf2f(hi)) : hi;
        }
    }
}

// One-time: k_pgemm B-fragments. Block-diagonal B (192 x 512):
// n-tiles 0-7 = W1 (k 0..63), 8-15 = W2 (k 0..63 -> rows 64..127),
// 16-23 = W3 for u (k 64..104), 24-31 = W3 for tt (k 128..168); 0 elsewhere.
// Frag layout [l][nt][ks2][hl][lane][8] with ks2 the relative kstep of the
// group's 2-kstep span (kb = 0 / 0 / 64 / 128).
__global__ __launch_bounds__(64) void k_wtb2(const float* __restrict__ convW,
                                             unsigned short* __restrict__ W3F2){
    int l  = blockIdx.x >> 5;
    int nt = blockIdx.x & 31;
    const float* Wl = convW + (size_t)l * 169 * C2;
    int lane = threadIdx.x;
    int kb = (nt < 16) ? 0 : (nt < 24 ? 64 : 128);
    for (int f = 0; f < 4; ++f){
        int ks2 = f >> 1, h = f & 1;
        unsigned short* dst = W3F2 + (size_t)l * PGFRAG
                            + (((size_t)nt * 2 + ks2) * 2 + h) * 512 + lane * 8;
        #pragma unroll
        for (int i = 0; i < 8; ++i){
            int kabs = kb + ks2 * 32 + (lane >> 4) * 8 + i;
            int n    = nt * 16 + (lane & 15);
            float wv = 0.f;
            if (nt < 8)        wv = Wl[kabs * C2 + n];
            else if (nt < 16)  wv = Wl[(64 + kabs) * C2 + (n - 128)];
            else if (nt < 24){ int kk = kabs - 64;  if (kk < Kc) wv = Wl[(C2 + kk) * C2 + (n - 256)]; }
            else             { int kk = kabs - 128; if (kk < Kc) wv = Wl[(C2 + kk) * C2 + (n - 384)]; }
            unsigned short hi = bfhi(wv);
            dst[i] = h ? bfhi(wv - bf2f(hi)) : hi;
        }
    }
}

// One-time: q3[l][c] = w3^T G w3
__global__ __launch_bounds__(128) void k_quad(const float* __restrict__ G,
                                              const float* __restrict__ convW,
                                              float* __restrict__ q3){
    int l = blockIdx.x, c = threadIdx.x;
    const float* Wl = convW + (size_t)l * 169 * C2;
    __shared__ float GL[Kc * Kc];
    for (int i = c; i < Kc * Kc; i += 128) GL[i] = G[i];
    float w3[Kc];
    #pragma unroll
    for (int k = 0; k < Kc; ++k) w3[k] = Wl[(C2 + k) * C2 + c];
    __syncthreads();
    float q = 0.f;
    for (int k = 0; k < Kc; ++k){
        float gw = 0.f;
        #pragma unroll
        for (int m = 0; m < Kc; ++m) gw += GL[k * Kc + m] * w3[m];
        q += w3[k] * gw;
    }
    q3[l * C2 + c] = q;
}

// MFMA front: per 16-row block compute [p1|p2|u|tt] = A(16x192) @ B(192x512),
// A = [fea | S pad | T pad] bf16 hi/lo (3-pass). Folds: BN2-update of prev
// layer into A staging; closed-form BN1 stats into epilogue. Writes p1,p2.
__global__ __launch_bounds__(512)
void k_pgemm(float* __restrict__ fea,
             const float* __restrict__ bl,
             const unsigned short* __restrict__ Bf,
             const float* __restrict__ ST,
             const float* __restrict__ cntf,
             const float* __restrict__ summed,
             const float* __restrict__ sum2Rp,
             const float* __restrict__ sq2Rp,
             const float* __restrict__ g2p,
             const float* __restrict__ b2p,
             float* __restrict__ p1,
             float* __restrict__ p2,
             float* __restrict__ sum1R,
             float* __restrict__ sq1R,
             int upd){
    int r0   = blockIdx.x * 16;
    int tid  = threadIdx.x;
    int lane = tid & 63;
    int w    = __builtin_amdgcn_readfirstlane(tid >> 6);  // wave 0..7
    __shared__ unsigned short AH[16 * PROW], AL[16 * PROW];  // 12.8 KB
    __shared__ float Db[16 * DROW];                           // 33 KB
    __shared__ float A2L[Fc], B2L[Fc], cnL[16];

    if (upd && tid < Fc){
        float s = 0.f, q = 0.f;
        for (int rr = 0; rr < NREP; ++rr){
            s += sum2Rp[rr * Fc + tid];
            q += sq2Rp[rr * Fc + tid];
        }
        float m = s * INV2;
        float v = q * INV2 - m * m;
        float A = g2p[tid] * rsqrtf(v + EPSBN);
        A2L[tid] = A;
        B2L[tid] = b2p[tid] - m * A;
    }
    if (tid < 16) cnL[tid] = cntf[r0 + tid];
    __syncthreads();

    // stage A rows (k<64: fea w/ inline BN2-update; 64..104: S; 128..168: T)
    for (int idx = tid; idx < 16 * 192; idx += 512){
        int r = idx / 192, k = idx - r * 192;
        int gr = r0 + r;
        float v = 0.f;
        if (k < 64){
            v = fea[gr * Fc + k];
            if (upd){
                v = sp_(v + summed[gr * Fc + k] * A2L[k] + B2L[k]);
                fea[gr * Fc + k] = v;
            }
        } else if (k < 105){
            v = ST[gr * (2 * Kc) + (k - 64)];
        } else if (k >= 128 && k < 169){
            v = ST[gr * (2 * Kc) + Kc + (k - 128)];
        }
        unsigned short hi = bfhi(v);
        AH[r * PROW + k] = hi;
        AL[r * PROW + k] = bfhi(v - bf2f(hi));
    }
    __syncthreads();

    // MFMA: wave w owns nt = w*4 .. w*4+3; group kbase by output kind.
    int q8   = (lane >> 4) * 8;
    int mrow = lane & 15;
    int kb   = (w < 4) ? 0 : (w < 6 ? 64 : 128);
    short8_t AH0 = *(const short8_t*)(&AH[mrow * PROW + kb + q8]);
    short8_t AH1 = *(const short8_t*)(&AH[mrow * PROW + kb + 32 + q8]);
    short8_t AL0 = *(const short8_t*)(&AL[mrow * PROW + kb + q8]);
    short8_t AL1 = *(const short8_t*)(&AL[mrow * PROW + kb + 32 + q8]);
    f32x4 acc[4] = {};
    #pragma unroll
    for (int nti = 0; nti < 4; ++nti){
        int nt = w * 4 + nti;
        const unsigned short* base = Bf + ((size_t)nt * 2) * 2 * 512;
        short8_t BH0 = *(const short8_t*)(base + 0 * 512 + lane * 8);
        short8_t BL0 = *(const short8_t*)(base + 1 * 512 + lane * 8);
        short8_t BH1 = *(const short8_t*)(base + 2 * 512 + lane * 8);
        short8_t BL1 = *(const short8_t*)(base + 3 * 512 + lane * 8);
        acc[nti] = __builtin_amdgcn_mfma_f32_16x16x32_bf16(AH0, BH0, acc[nti], 0, 0, 0);
        acc[nti] = __builtin_amdgcn_mfma_f32_16x16x32_bf16(AH0, BL0, acc[nti], 0, 0, 0);
        acc[nti] = __builtin_amdgcn_mfma_f32_16x16x32_bf16(AL0, BH0, acc[nti], 0, 0, 0);
        acc[nti] = __builtin_amdgcn_mfma_f32_16x16x32_bf16(AH1, BH1, acc[nti], 0, 0, 0);
        acc[nti] = __builtin_amdgcn_mfma_f32_16x16x32_bf16(AH1, BL1, acc[nti], 0, 0, 0);
        acc[nti] = __builtin_amdgcn_mfma_f32_16x16x32_bf16(AL1, BH1, acc[nti], 0, 0, 0);
    }
    #pragma unroll
    for (int nti = 0; nti < 4; ++nti){
        int col = (w * 4 + nti) * 16 + mrow;
        #pragma unroll
        for (int rg = 0; rg < 4; ++rg){
            int row = (lane >> 4) * 4 + rg;
            Db[row * DROW + col] = acc[nti][rg];
        }
    }
    __syncthreads();

    // epilogue A: closed-form BN1 stats (verified R12 formulas)
    {
        int c = tid >> 2, rq = tid & 3;
        float blc = bl[c];
        float s1 = 0.f, q1 = 0.f;
        #pragma unroll
        for (int i = 0; i < 4; ++i){
            int r = rq * 4 + i;
            float a1 = Db[r * DROW + c] + blc;
            float a2 = Db[r * DROW + 128 + c];
            float u  = Db[r * DROW + 256 + c];
            float tt = Db[r * DROW + 384 + c];
            float cn = cnL[r];
            s1 += (float)NAt * a1 + cn * a2 + u;
            q1 += (float)NAt * a1 * a1 + cn * a2 * a2
                + 2.f * cn * a1 * a2 + 2.f * a1 * u + 2.f * a2 * tt;
        }
        s1 += __shfl_xor(s1, 1);  s1 += __shfl_xor(s1, 2);
        q1 += __shfl_xor(q1, 1);  q1 += __shfl_xor(q1, 2);
        if (rq == 0){
            int slot = blockIdx.x & (NREP - 1);
            atomicAdd(&sum1R[slot * C2 + c], s1);
            atomicAdd(&sq1R[slot * C2 + c], q1);
        }
    }
    // epilogue B: p1/p2 writeback (p1 includes conv bias, matching k_apply)
    for (int idx = tid; idx < 16 * 256; idx += 512){
        int r = idx >> 8, cc = idx & 255;
        if (cc < 128) p1[(r0 + r) * C2 + cc]        = Db[r * DROW + cc] + bl[cc];
        else          p2[(r0 + r) * C2 + (cc - 128)] = Db[r * DROW + cc];
    }
}

// Pass 2 (MFMA, identical to R13 — verified).
__global__ __launch_bounds__(512)
void k_apply(const float* __restrict__ nbr,
             const int*   __restrict__ adj,
             const unsigned short* __restrict__ W3Fl,
             const float* __restrict__ p1,
             const float* __restrict__ p2,
             const float* __restrict__ sum1R,
             const float* __restrict__ sq1R,
             const float* __restrict__ qv,
             const float* __restrict__ g1,
             const float* __restrict__ b1,
             float* __restrict__ summed,
             float* __restrict__ sum2R,
             float* __restrict__ sq2R){
    int r    = blockIdx.x;
    int tid  = threadIdx.x;
    int lane = tid & 63;
    int w    = __builtin_amdgcn_readfirstlane(tid >> 6);
    int ntF  = w & 3;
    int mh   = w >> 2;

    __shared__ unsigned short sAH[NAt * AROW];
    __shared__ unsigned short sAL[NAt * AROW];
    __shared__ float AJ[NAt];
    __shared__ float PL1[C2], PL2[C2], A1L[C2], B1L[C2];
    __shared__ float TpW[8][16];

    short8_t BH[2][2], BL[2][2];
    #pragma unroll
    for (int ni = 0; ni < 2; ++ni){
        int nt = ntF + ni * 4;
        #pragma unroll
        for (int ks = 0; ks < 2; ++ks){
            int fidH = (nt * 2 + ks) * 2;
            BH[ni][ks] = *(const short8_t*)(W3Fl + fidH * 512 + lane * 8);
            BL[ni][ks] = *(const short8_t*)(W3Fl + (fidH + 1) * 512 + lane * 8);
        }
    }

    const float* nb = nbr + (size_t)r * (NAt * Kc);
    for (int idx = tid; idx < NAt * Kc; idx += 512){
        int j = idx / Kc, k = idx - j * Kc;
        float x = nb[idx];
        unsigned short hi = bfhi(x);
        sAH[j * AROW + k] = hi;
        sAL[j * AROW + k] = bfhi(x - bf2f(hi));
    }
    for (int idx = tid; idx < NAt * 23; idx += 512){
        int j = idx / 23, k = Kc + (idx - j * 23);
        sAH[j * AROW + k] = 0;
        sAL[j * AROW + k] = 0;
    }
    if (tid < C2){
        int c = tid;
        float s = 0.f, q = 0.f;
        for (int rr = 0; rr < NREP; ++rr){ s += sum1R[rr * C2 + c]; q += sq1R[rr * C2 + c]; }
        float m = s * INV1;
        float v = (q + qv[c]) * INV1 - m * m;
        float A = g1[c] * rsqrtf(v + EPSBN);
        A1L[c] = A;
        B1L[c] = b1[c] - m * A;
    } else if (tid < 256){
        PL1[tid - 128] = p1[r * C2 + tid - 128];
    } else if (tid < 384){
        PL2[tid - 256] = p2[r * C2 + tid - 256];
    } else if (tid < 480){
        AJ[tid - 384] = (float)adj[r * NAt + tid - 384];
    }
    __syncthreads();

    f32x4 acc[3][2] = {};
    int q4 = (lane >> 4) * 8;
    #pragma unroll
    for (int mt = 0; mt < 3; ++mt){
        int jrow = (mh * 48 + mt * 16 + (lane & 15)) * AROW;
        short8_t AH0 = *(const short8_t*)(&sAH[jrow + q4]);
        short8_t AH1 = *(const short8_t*)(&sAH[jrow + 32 + q4]);
        short8_t AL0 = *(const short8_t*)(&sAL[jrow + q4]);
        short8_t AL1 = *(const short8_t*)(&sAL[jrow + 32 + q4]);
        #pragma unroll
        for (int ni = 0; ni < 2; ++ni){
            acc[mt][ni] = __builtin_amdgcn_mfma_f32_16x16x32_bf16(AH0, BH[ni][0], acc[mt][ni], 0, 0, 0);
            acc[mt][ni] = __builtin_amdgcn_mfma_f32_16x16x32_bf16(AH0, BL[ni][0], acc[mt][ni], 0, 0, 0);
            acc[mt][ni] = __builtin_amdgcn_mfma_f32_16x16x32_bf16(AL0, BH[ni][0], acc[mt][ni], 0, 0, 0);
            acc[mt][ni] = __builtin_amdgcn_mfma_f32_16x16x32_bf16(AH1, BH[ni][1], acc[mt][ni], 0, 0, 0);
            acc[mt][ni] = __builtin_amdgcn_mfma_f32_16x16x32_bf16(AH1, BL[ni][1], acc[mt][ni], 0, 0, 0);
            acc[mt][ni] = __builtin_amdgcn_mfma_f32_16x16x32_bf16(AL1, BH[ni][1], acc[mt][ni], 0, 0, 0);
        }
    }

    int cF = ntF * 16 + (lane & 15);
    int cC = cF + 64;
    float p1F = PL1[cF], p2F = PL2[cF], A1F = A1L[cF], B1F = B1L[cF];
    float p1C = PL1[cC], p2C = PL2[cC], A1C = A1L[cC], B1C = B1L[cC];
    float tsum = 0.f;
    #pragma unroll
    for (int mt = 0; mt < 3; ++mt){
        #pragma unroll
        for (int rg = 0; rg < 4; ++rg){
            int j = mh * 48 + mt * 16 + (lane >> 4) * 4 + rg;
            float ajf = AJ[j];
            float gf = (p1F + ajf * p2F + acc[mt][0][rg]) * A1F + B1F;
            float gc = (p1C + ajf * p2C + acc[mt][1][rg]) * A1C + B1C;
            tsum += sgm_(gf) * sp_(gc);
        }
    }
    tsum += __shfl_xor(tsum, 16);
    tsum += __shfl_xor(tsum, 32);
    if (lane < 16) TpW[w][lane] = tsum;
    __syncthreads();
    if (tid < Fc){
        int f = tid;
        float s = TpW[f >> 4][f & 15] + TpW[(f >> 4) + 4][f & 15];
        summed[r * Fc + f] = s;
        int slot = blockIdx.x & (NREP - 1);
        atomicAdd(&sum2R[slot * Fc + f], s);
        atomicAdd(&sq2R[slot * Fc + f], s * s);
    }
}

// Tail (identical to R13).
__global__ __launch_bounds__(128) void k_final(const float* __restrict__ fea,
                                               const float* __restrict__ summed,
                                               const float* __restrict__ sum2R,
                                               const float* __restrict__ sq2R,
                                               const float* __restrict__ g2,
                                               const float* __restrict__ b2,
                                               const float* __restrict__ fcW,
                                               const float* __restrict__ fcb,
                                               const float* __restrict__ outW,
                                               const float* __restrict__ outb,
                                               float* __restrict__ out){
    int b = blockIdx.x;
    int t = threadIdx.x;
    __shared__ float spc[Fc];
    __shared__ float red[Hc];
    if (t < Fc){
        float s = 0.f, q = 0.f;
        for (int r = 0; r < NREP; ++r){ s += sum2R[r * Fc + t]; q += sq2R[r * Fc + t]; }
        float m  = s * INV2;
        float v  = q * INV2 - m * m;
        float A2 = g2[t] * rsqrtf(v + EPSBN);
        float B2 = b2[t] - m * A2;
        float acc = 0.f;
        for (int i = 0; i < NAt; ++i){
            int idx = (b * NAt + i) * Fc + t;
            acc += sp_(fea[idx] + summed[idx] * A2 + B2);
        }
        spc[t] = sp_(acc * (1.f / NAt));
    }
    __syncthreads();
    float h = fcb[t];
    #pragma unroll 4
    for (int f = 0; f < Fc; ++f) h += spc[f] * fcW[f * Hc + t];
    h = sp_(h);
    red[t] = h * outW[t];
    __syncthreads();
    for (int off = 64; off > 0; off >>= 1){
        if (t < off) red[t] += red[t + off];
        __syncthreads();
    }
    if (t == 0) out[b] = red[0] + outb[0];
}

extern "C" void kernel_launch(void* const* d_in, const int* in_sizes, int n_in,
                              void* d_out, int out_size, void* d_ws, size_t ws_size,
                              hipStream_t stream){
    const float* atom  = (const float*)d_in[0];
    const float* nbr   = (const float*)d_in[1];
    const int*   adj   = (const int*)  d_in[2];
    const float* embW  = (const float*)d_in[3];
    const float* embB  = (const float*)d_in[4];
    const float* convW = (const float*)d_in[5];
    const float* convB = (const float*)d_in[6];
    const float* bn1g  = (const float*)d_in[7];
    const float* bn1b  = (const float*)d_in[8];
    const float* bn2g  = (const float*)d_in[9];
    const float* bn2b  = (const float*)d_in[10];
    const float* fcW   = (const float*)d_in[11];
    const float* fcb   = (const float*)d_in[12];
    const float* outW  = (const float*)d_in[13];
    const float* outb  = (const float*)d_in[14];
    float* out = (float*)d_out;
    float* ws  = (float*)d_ws;

    const int ROWS = N0c * NAt;            // 1536
    float* fea    = ws;                    // 98304
    float* p1     = ws + 98304;            // 196608
    float* p2     = ws + 294912;           // 196608
    float* summed = ws + 491520;           // 98304
    float* SRL    = ws + 589824;           // 3 * 12288
    float* ST     = ws + 626688;           // 125952
    float* cntf   = ws + 752640;           // 1536
    float* q3     = ws + 754176;           // 384
    unsigned short* W3F  = (unsigned short*)(ws + 754560);  // 49152 us = 24576 f
    unsigned short* W3F2 = (unsigned short*)(ws + 779136);  // 3*131072 us = 196608 f... (98304 f)
    const size_t PERS = 877440;

    size_t ws_f = ws_size / sizeof(float);
    int nblk; float *pG, *G;
    if (ws_f >= PERS + (size_t)1536 * 1681 + 1681 + 64){
        nblk = 1536; pG = ws + PERS; G = pG + (size_t)nblk * 1681;
    } else if (ws_f >= PERS + (size_t)768 * 1681 + 1681 + 64){
        nblk = 768;  pG = ws + PERS; G = pG + (size_t)nblk * 1681;
    } else if (ws_f >= PERS + (size_t)384 * 1681 + 1681 + 64){
        nblk = 384;  pG = ws + PERS; G = pG + (size_t)nblk * 1681;
    } else {
        // compact overlay: pG over fea..SRL (dead until k_embed); G inside ST
        // (written by k_pre AFTER k_quad consumed G).
        nblk = 384;  pG = ws;        G = ws + 650000;
    }
    int rpb = 1536 / nblk;
    int ph  = nblk / 96;

    hipMemsetAsync(G, 0, Kc * Kc * sizeof(float), stream);
    k_gram <<<nblk, 128, 0, stream>>>(nbr, pG, rpb);
    k_gred <<<27 * ph, 64, 0, stream>>>(pG, G);
    k_wtb  <<<NCc, 256, 0, stream>>>(convW, W3F);
    k_wtb2 <<<NCc * 32, 64, 0, stream>>>(convW, W3F2);
    k_quad <<<NCc, C2, 0, stream>>>(G, convW, q3);
    k_embed<<<ROWS / 4, 256, 0, stream>>>(atom, embW, embB, fea);
    k_pre  <<<ROWS, 256, 0, stream>>>(nbr, adj, ST, cntf);
    hipMemsetAsync(SRL, 0, 3 * SRL_STRIDE * sizeof(float), stream);

    for (int l = 0; l < NCc; ++l){
        const float* bl    = convB + l * C2;
        const unsigned short* W3Fl  = W3F  + (size_t)l * WFRAG;
        const unsigned short* W3F2l = W3F2 + (size_t)l * PGFRAG;
        float* sum1R = SRL + l * SRL_STRIDE;
        float* sq1R  = sum1R + 4096;
        float* sum2R = sum1R + 8192;
        float* sq2R  = sum1R + 10240;
        const float* sum2Rp = (l > 0) ? SRL + (l - 1) * SRL_STRIDE + 8192 : SRL;
        const float* sq2Rp  = (l > 0) ? SRL + (l - 1) * SRL_STRIDE + 10240 : SRL;
        const float* g2p    = bn2g + (l > 0 ? (l - 1) : 0) * Fc;
        const float* b2p    = bn2b + (l > 0 ? (l - 1) : 0) * Fc;

        k_pgemm <<<ROWS / 16, 512, 0, stream>>>(fea, bl, W3F2l, ST, cntf,
                                                summed, sum2Rp, sq2Rp, g2p, b2p,
                                                p1, p2, sum1R, sq1R,
                                                l > 0 ? 1 : 0);
        k_apply <<<ROWS, 512, 0, stream>>>(nbr, adj, W3Fl, p1, p2,
                                           sum1R, sq1R, q3 + l * C2,
                                           bn1g + l * C2, bn1b + l * C2,
                                           summed, sum2R, sq2R);
    }

    k_final<<<N0c, Hc, 0, stream>>>(fea, summed,
                                    SRL + 2 * SRL_STRIDE + 8192,
                                    SRL + 2 * SRL_STRIDE + 10240,
                                    bn2g + 2 * Fc, bn2b + 2 * Fc,
                                    fcW, fcb, outW, outb, out);
}

// Round 15
// 294.021 us; speedup vs baseline: 1.0341x; 1.0341x over previous
//
#include <hip/hip_runtime.h>
#include <math.h>

#define N0c   16
#define NAt   96
#define ORIG  92
#define Fc    64
#define Kc    41
#define Hc    128
#define NCc   3
#define C2    128   // 2F
#define EPSBN 1e-5f
#define JG    4
#define JPW   (NAt / JG)
#define NREP  32    // atomic replica slots
#define SRL_STRIDE 12288   // per-layer replica block
#define AROW  72    // k_apply LDS A row stride (ushorts)
#define WFRAG 16384 // ushorts per layer in W3F (k_apply B frags)
#define INV1  (1.f / (float)(N0c * NAt * NAt))
#define INV2  (1.f / (float)(N0c * NAt))

typedef __attribute__((ext_vector_type(8))) short short8_t;   // 8 bf16
typedef __attribute__((ext_vector_type(4))) float f32x4;

__device__ __forceinline__ float sp_(float x){
    return fmaxf(x, 0.f) + __logf(1.f + __expf(-fabsf(x)));
}
__device__ __forceinline__ float sgm_(float x){
    return 1.f / (1.f + __expf(-x));
}
__device__ __forceinline__ unsigned short bfhi(float x){
    union { float f; unsigned u; } v; v.f = x;
    unsigned r = v.u + 0x7fff + ((v.u >> 16) & 1);   // RNE to bf16
    return (unsigned short)(r >> 16);
}
__device__ __forceinline__ float bf2f(unsigned short h){
    union { float f; unsigned u; } v; v.u = ((unsigned)h) << 16; return v.f;
}

// fea = atom @ emb_W + emb_b
__global__ __launch_bounds__(256) void k_embed(const float* __restrict__ atom,
                                               const float* __restrict__ W,
                                               const float* __restrict__ b,
                                               float* __restrict__ fea){
    int row = blockIdx.x * 4 + (threadIdx.x >> 6);
    int f   = threadIdx.x & 63;
    const float* ar = atom + row * ORIG;
    float acc = b[f];
    #pragma unroll 4
    for (int o = 0; o < ORIG; ++o) acc += ar[o] * W[o * Fc + f];
    fea[row * Fc + f] = acc;
}

// One-time: S_r, T_r, cnt_r.
__global__ __launch_bounds__(256) void k_pre(const float* __restrict__ nbr,
                                             const int*   __restrict__ adj,
                                             float* __restrict__ ST,
                                             float* __restrict__ cntf){
    int r    = blockIdx.x;
    int lane = threadIdx.x & 63;
    int jg   = __builtin_amdgcn_readfirstlane(threadIdx.x >> 6);
    __shared__ float rS[JG][Kc], rT[JG][Kc], rc[JG];
    float S = 0.f, T = 0.f, cn = 0.f;
    int j0 = jg * JPW;
    for (int j = j0; j < j0 + JPW; ++j){
        float a = (float)adj[r * NAt + j];
        float v = (lane < Kc) ? nbr[((size_t)r * NAt + j) * Kc + lane] : 0.f;
        S += v; T += a * v; cn += a;
    }
    if (lane < Kc){ rS[jg][lane] = S; rT[jg][lane] = T; }
    if (lane == 0) rc[jg] = cn;
    __syncthreads();
    int t = threadIdx.x;
    if (t < Kc){
        ST[r * (2 * Kc) + t]      = rS[0][t] + rS[1][t] + rS[2][t] + rS[3][t];
        ST[r * (2 * Kc) + Kc + t] = rT[0][t] + rT[1][t] + rT[2][t] + rT[3][t];
    }
    if (t == 0) cntf[r] = rc[0] + rc[1] + rc[2] + rc[3];
}

// Gram partials (identical to R13).
__global__ __launch_bounds__(128) void k_gram(const float* __restrict__ nbr,
                                              float* __restrict__ pG, int rpb){
    int blk = blockIdx.x;
    int t   = threadIdx.x;
    int k   = (t % 21) * 2;
    int lb  = (t / 21) * 7;
    __shared__ float L[NAt * Kc];
    float a0[7] = {0,0,0,0,0,0,0}, a1[7] = {0,0,0,0,0,0,0};
    for (int rr = 0; rr < rpb; ++rr){
        int r = blk * rpb + rr;
        __syncthreads();
        for (int i = t; i < NAt * Kc; i += 128)
            L[i] = nbr[(size_t)r * NAt * Kc + i];
        __syncthreads();
        if (t < 126){
            for (int j = 0; j < NAt; ++j){
                float vk0 = L[j * Kc + k];
                float vk1 = (k + 1 < Kc) ? L[j * Kc + k + 1] : 0.f;
                #pragma unroll
                for (int m = 0; m < 7; ++m){
                    if (lb + m < Kc){
                        float lv = L[j * Kc + lb + m];
                        a0[m] += vk0 * lv;
                        a1[m] += vk1 * lv;
                    }
                }
            }
        }
    }
    if (t < 126){
        float* dst = pG + (size_t)blk * (Kc * Kc);
        #pragma unroll
        for (int m = 0; m < 7; ++m){
            if (lb + m < Kc){
                dst[k * Kc + lb + m] = a0[m];
                if (k + 1 < Kc) dst[(k + 1) * Kc + lb + m] = a1[m];
            }
        }
    }
}

__global__ __launch_bounds__(64) void k_gred(const float* __restrict__ pG,
                                             float* __restrict__ G){
    int i  = (blockIdx.x % 27) * 64 + threadIdx.x;
    int b0 = (blockIdx.x / 27) * 96;
    if (i < Kc * Kc){
        float s = 0.f;
        #pragma unroll 4
        for (int b = b0; b < b0 + 96; ++b) s += pG[(size_t)b * (Kc * Kc) + i];
        atomicAdd(&G[i], s);
    }
}

// One-time: transposed padded W3 float (for k_front): W3T[l][c][44]
__global__ void k_wt(const float* __restrict__ convW, float* __restrict__ W3T){
    int l = blockIdx.x, c = threadIdx.x;
    const float* Wl = convW + (size_t)l * 169 * C2;
    float* dst = W3T + ((size_t)l * C2 + c) * 44;
    for (int k = 0; k < Kc; ++k) dst[k] = Wl[(C2 + k) * C2 + c];
    dst[41] = 0.f; dst[42] = 0.f; dst[43] = 0.f;
}

// One-time: k_apply B-fragments (identical to R13, verified).
__global__ __launch_bounds__(256) void k_wtb(const float* __restrict__ convW,
                                             unsigned short* __restrict__ W3F){
    int l = blockIdx.x;
    const float* Wl = convW + (size_t)l * 169 * C2;
    for (int it = 0; it < 8; ++it){
        int idx  = threadIdx.x + it * 256;
        int lane = idx & 63;
        int fid  = idx >> 6;
        int h    = fid & 1;
        int ks   = (fid >> 1) & 1;
        int nt   = fid >> 2;
        int n    = nt * 16 + (lane & 15);
        unsigned short* dst = W3F + (size_t)l * WFRAG + fid * 512 + lane * 8;
        #pragma unroll
        for (int i = 0; i < 8; ++i){
            int k = ks * 32 + (lane >> 4) * 8 + i;
            float w = (k < Kc) ? Wl[(C2 + k) * C2 + n] : 0.f;
            unsigned short hi = bfhi(w);
            dst[i] = h ? bfhi(w - bf2f(hi)) : hi;
        }
    }
}

// One-time: q3[l][c] = w3^T G w3
__global__ __launch_bounds__(128) void k_quad(const float* __restrict__ G,
                                              const float* __restrict__ convW,
                                              float* __restrict__ q3){
    int l = blockIdx.x, c = threadIdx.x;
    const float* Wl = convW + (size_t)l * 169 * C2;
    __shared__ float GL[Kc * Kc];
    for (int i = c; i < Kc * Kc; i += 128) GL[i] = G[i];
    float w3[Kc];
    #pragma unroll
    for (int k = 0; k < Kc; ++k) w3[k] = Wl[(C2 + k) * C2 + c];
    __syncthreads();
    float q = 0.f;
    for (int k = 0; k < Kc; ++k){
        float gw = 0.f;
        #pragma unroll
        for (int m = 0; m < Kc; ++m) gw += GL[k * Kc + m] * w3[m];
        q += w3[k] * gw;
    }
    q3[l * C2 + c] = q;
}

// Front v3: ONE row per block, 256 thr (grid 1536 -> 6 waves/SIMD, 4x R13).
// f-range split across wave-pairs (half = tid>>7, wave-uniform): each thread
// does 64 Wl loads (was 256); S-dot on half 0, T-dot on half 1 (41 uniform
// loads each, was 82). w3 consumed inline via float4 — NO register array
// (avoids the AGPR-offload trap). Halves combine via LDS. Stats formulas
// unchanged (verified R6+). BN2-update of prev layer folded (R12 scheme).
__global__ __launch_bounds__(256)
void k_front(float* __restrict__ fea,
             const float* __restrict__ Wl,
             const float* __restrict__ bl,
             const float* __restrict__ W3Tl,
             const float* __restrict__ ST,
             const float* __restrict__ cntf,
             float* __restrict__ p1,
             float* __restrict__ p2,
             float* __restrict__ sum1R,
             float* __restrict__ sq1R,
             const float* __restrict__ summed,
             const float* __restrict__ sum2Rp,
             const float* __restrict__ sq2Rp,
             const float* __restrict__ g2p,
             const float* __restrict__ b2p,
             int upd){
    int r    = blockIdx.x;
    int tid  = threadIdx.x;
    int c    = tid & 127;
    int half = __builtin_amdgcn_readfirstlane(tid >> 7);   // 0: waves 0-1, 1: waves 2-3
    __shared__ float F[Fc];
    __shared__ float A2L[Fc], B2L[Fc];
    __shared__ float P1h[C2], P2h[C2], TTs[C2];

    if (upd){
        if (tid < Fc){
            float s = 0.f, q = 0.f;
            for (int rr = 0; rr < NREP; ++rr){
                s += sum2Rp[rr * Fc + tid];
                q += sq2Rp[rr * Fc + tid];
            }
            float m = s * INV2;
            float v = q * INV2 - m * m;
            float A = g2p[tid] * rsqrtf(v + EPSBN);
            A2L[tid] = A;
            B2L[tid] = b2p[tid] - m * A;
        }
        __syncthreads();
        if (tid < Fc){
            float nv = sp_(fea[r * Fc + tid] + summed[r * Fc + tid] * A2L[tid] + B2L[tid]);
            F[tid] = nv;
            fea[r * Fc + tid] = nv;          // persist for k_final path
        }
        __syncthreads();
    } else {
        if (tid < Fc) F[tid] = fea[r * Fc + tid];
        __syncthreads();
    }

    // p12 partial over f in [half*32, half*32+32)
    float a1p = 0.f, a2p = 0.f;
    int f0 = half * 32;
    #pragma unroll 8
    for (int f = f0; f < f0 + 32; ++f){
        float fv = F[f];                     // LDS broadcast
        a1p += fv * Wl[f * C2 + c];
        a2p += fv * Wl[(Fc + f) * C2 + c];
    }
    // dot: half 0 -> u = S·w3 ; half 1 -> tt = T·w3 (uniform s_loads of S/T)
    const float* wt = W3Tl + c * 44;         // per-lane float4 loads
    const float* Sr = ST + r * (2 * Kc) + half * Kc;
    float dot = 0.f;
    #pragma unroll
    for (int k = 0; k < 40; k += 4){
        float4 wv = *(const float4*)(wt + k);
        dot += Sr[k] * wv.x + Sr[k + 1] * wv.y + Sr[k + 2] * wv.z + Sr[k + 3] * wv.w;
    }
    dot += Sr[40] * wt[40];

    if (half == 1){ P1h[c] = a1p; P2h[c] = a2p; TTs[c] = dot; }
    __syncthreads();
    if (half == 0){
        float a1 = a1p + P1h[c] + bl[c];
        float a2 = a2p + P2h[c];
        float u  = dot;
        float tt = TTs[c];
        p1[r * C2 + c] = a1;
        p2[r * C2 + c] = a2;
        float cn = cntf[r];
        float s1 = (float)NAt * a1 + cn * a2 + u;
        float q1 = (float)NAt * a1 * a1 + cn * a2 * a2
                 + 2.f * cn * a1 * a2 + 2.f * a1 * u + 2.f * a2 * tt;
        int slot = blockIdx.x & (NREP - 1);
        atomicAdd(&sum1R[slot * C2 + c], s1);
        atomicAdd(&sq1R[slot * C2 + c], q1);
    }
}

// Pass 2 (MFMA, identical to R13 — verified, ~35 us).
__global__ __launch_bounds__(512)
void k_apply(const float* __restrict__ nbr,
             const int*   __restrict__ adj,
             const unsigned short* __restrict__ W3Fl,
             const float* __restrict__ p1,
             const float* __restrict__ p2,
             const float* __restrict__ sum1R,
             const float* __restrict__ sq1R,
             const float* __restrict__ qv,
             const float* __restrict__ g1,
             const float* __restrict__ b1,
             float* __restrict__ summed,
             float* __restrict__ sum2R,
             float* __restrict__ sq2R){
    int r    = blockIdx.x;
    int tid  = threadIdx.x;
    int lane = tid & 63;
    int w    = __builtin_amdgcn_readfirstlane(tid >> 6);
    int ntF  = w & 3;
    int mh   = w >> 2;

    __shared__ unsigned short sAH[NAt * AROW];
    __shared__ unsigned short sAL[NAt * AROW];
    __shared__ float AJ[NAt];
    __shared__ float PL1[C2], PL2[C2], A1L[C2], B1L[C2];
    __shared__ float TpW[8][16];

    short8_t BH[2][2], BL[2][2];
    #pragma unroll
    for (int ni = 0; ni < 2; ++ni){
        int nt = ntF + ni * 4;
        #pragma unroll
        for (int ks = 0; ks < 2; ++ks){
            int fidH = (nt * 2 + ks) * 2;
            BH[ni][ks] = *(const short8_t*)(W3Fl + fidH * 512 + lane * 8);
            BL[ni][ks] = *(const short8_t*)(W3Fl + (fidH + 1) * 512 + lane * 8);
        }
    }

    const float* nb = nbr + (size_t)r * (NAt * Kc);
    for (int idx = tid; idx < NAt * Kc; idx += 512){
        int j = idx / Kc, k = idx - j * Kc;
        float x = nb[idx];
        unsigned short hi = bfhi(x);
        sAH[j * AROW + k] = hi;
        sAL[j * AROW + k] = bfhi(x - bf2f(hi));
    }
    for (int idx = tid; idx < NAt * 23; idx += 512){
        int j = idx / 23, k = Kc + (idx - j * 23);
        sAH[j * AROW + k] = 0;
        sAL[j * AROW + k] = 0;
    }
    if (tid < C2){
        int c = tid;
        float s = 0.f, q = 0.f;
        for (int rr = 0; rr < NREP; ++rr){ s += sum1R[rr * C2 + c]; q += sq1R[rr * C2 + c]; }
        float m = s * INV1;
        float v = (q + qv[c]) * INV1 - m * m;
        float A = g1[c] * rsqrtf(v + EPSBN);
        A1L[c] = A;
        B1L[c] = b1[c] - m * A;
    } else if (tid < 256){
        PL1[tid - 128] = p1[r * C2 + tid - 128];
    } else if (tid < 384){
        PL2[tid - 256] = p2[r * C2 + tid - 256];
    } else if (tid < 480){
        AJ[tid - 384] = (float)adj[r * NAt + tid - 384];
    }
    __syncthreads();

    f32x4 acc[3][2] = {};
    int q4 = (lane >> 4) * 8;
    #pragma unroll
    for (int mt = 0; mt < 3; ++mt){
        int jrow = (mh * 48 + mt * 16 + (lane & 15)) * AROW;
        short8_t AH0 = *(const short8_t*)(&sAH[jrow + q4]);
        short8_t AH1 = *(const short8_t*)(&sAH[jrow + 32 + q4]);
        short8_t AL0 = *(const short8_t*)(&sAL[jrow + q4]);
        short8_t AL1 = *(const short8_t*)(&sAL[jrow + 32 + q4]);
        #pragma unroll
        for (int ni = 0; ni < 2; ++ni){
            acc[mt][ni] = __builtin_amdgcn_mfma_f32_16x16x32_bf16(AH0, BH[ni][0], acc[mt][ni], 0, 0, 0);
            acc[mt][ni] = __builtin_amdgcn_mfma_f32_16x16x32_bf16(AH0, BL[ni][0], acc[mt][ni], 0, 0, 0);
            acc[mt][ni] = __builtin_amdgcn_mfma_f32_16x16x32_bf16(AL0, BH[ni][0], acc[mt][ni], 0, 0, 0);
            acc[mt][ni] = __builtin_amdgcn_mfma_f32_16x16x32_bf16(AH1, BH[ni][1], acc[mt][ni], 0, 0, 0);
            acc[mt][ni] = __builtin_amdgcn_mfma_f32_16x16x32_bf16(AH1, BL[ni][1], acc[mt][ni], 0, 0, 0);
            acc[mt][ni] = __builtin_amdgcn_mfma_f32_16x16x32_bf16(AL1, BH[ni][1], acc[mt][ni], 0, 0, 0);
        }
    }

    int cF = ntF * 16 + (lane & 15);
    int cC = cF + 64;
    float p1F = PL1[cF], p2F = PL2[cF], A1F = A1L[cF], B1F = B1L[cF];
    float p1C = PL1[cC], p2C = PL2[cC], A1C = A1L[cC], B1C = B1L[cC];
    float tsum = 0.f;
    #pragma unroll
    for (int mt = 0; mt < 3; ++mt){
        #pragma unroll
        for (int rg = 0; rg < 4; ++rg){
            int j = mh * 48 + mt * 16 + (lane >> 4) * 4 + rg;
            float ajf = AJ[j];
            float gf = (p1F + ajf * p2F + acc[mt][0][rg]) * A1F + B1F;
            float gc = (p1C + ajf * p2C + acc[mt][1][rg]) * A1C + B1C;
            tsum += sgm_(gf) * sp_(gc);
        }
    }
    tsum += __shfl_xor(tsum, 16);
    tsum += __shfl_xor(tsum, 32);
    if (lane < 16) TpW[w][lane] = tsum;
    __syncthreads();
    if (tid < Fc){
        int f = tid;
        float s = TpW[f >> 4][f & 15] + TpW[(f >> 4) + 4][f & 15];
        summed[r * Fc + f] = s;
        int slot = blockIdx.x & (NREP - 1);
        atomicAdd(&sum2R[slot * Fc + f], s);
        atomicAdd(&sq2R[slot * Fc + f], s * s);
    }
}

// Tail (identical to R13).
__global__ __launch_bounds__(128) void k_final(const float* __restrict__ fea,
                                               const float* __restrict__ summed,
                                               const float* __restrict__ sum2R,
                                               const float* __restrict__ sq2R,
                                               const float* __restrict__ g2,
                                               const float* __restrict__ b2,
                                               const float* __restrict__ fcW,
                                               const float* __restrict__ fcb,
                                               const float* __restrict__ outW,
                                               const float* __restrict__ outb,
                                               float* __restrict__ out){
    int b = blockIdx.x;
    int t = threadIdx.x;
    __shared__ float spc[Fc];
    __shared__ float red[Hc];
    if (t < Fc){
        float s = 0.f, q = 0.f;
        for (int r = 0; r < NREP; ++r){ s += sum2R[r * Fc + t]; q += sq2R[r * Fc + t]; }
        float m  = s * INV2;
        float v  = q * INV2 - m * m;
        float A2 = g2[t] * rsqrtf(v + EPSBN);
        float B2 = b2[t] - m * A2;
        float acc = 0.f;
        for (int i = 0; i < NAt; ++i){
            int idx = (b * NAt + i) * Fc + t;
            acc += sp_(fea[idx] + summed[idx] * A2 + B2);
        }
        spc[t] = sp_(acc * (1.f / NAt));
    }
    __syncthreads();
    float h = fcb[t];
    #pragma unroll 4
    for (int f = 0; f < Fc; ++f) h += spc[f] * fcW[f * Hc + t];
    h = sp_(h);
    red[t] = h * outW[t];
    __syncthreads();
    for (int off = 64; off > 0; off >>= 1){
        if (t < off) red[t] += red[t + off];
        __syncthreads();
    }
    if (t == 0) out[b] = red[0] + outb[0];
}

extern "C" void kernel_launch(void* const* d_in, const int* in_sizes, int n_in,
                              void* d_out, int out_size, void* d_ws, size_t ws_size,
                              hipStream_t stream){
    const float* atom  = (const float*)d_in[0];
    const float* nbr   = (const float*)d_in[1];
    const int*   adj   = (const int*)  d_in[2];
    const float* embW  = (const float*)d_in[3];
    const float* embB  = (const float*)d_in[4];
    const float* convW = (const float*)d_in[5];
    const float* convB = (const float*)d_in[6];
    const float* bn1g  = (const float*)d_in[7];
    const float* bn1b  = (const float*)d_in[8];
    const float* bn2g  = (const float*)d_in[9];
    const float* bn2b  = (const float*)d_in[10];
    const float* fcW   = (const float*)d_in[11];
    const float* fcb   = (const float*)d_in[12];
    const float* outW  = (const float*)d_in[13];
    const float* outb  = (const float*)d_in[14];
    float* out = (float*)d_out;
    float* ws  = (float*)d_ws;

    const int ROWS = N0c * NAt;            // 1536
    float* fea    = ws;                    // 98304
    float* p1     = ws + 98304;            // 196608
    float* p2     = ws + 294912;           // 196608
    float* summed = ws + 491520;           // 98304
    float* SRL    = ws + 589824;           // 3 * 12288
    float* ST     = ws + 626688;           // 125952
    float* cntf   = ws + 752640;           // 1536
    float* q3     = ws + 754176;           // 384
    float* W3T    = ws + 754560;           // 16896
    unsigned short* W3F = (unsigned short*)(ws + 771456);  // 3*16384 us = 24576 f
    const size_t PERS = 796032;

    size_t ws_f = ws_size / sizeof(float);
    int nblk; float *pG, *G;
    if (ws_f >= PERS + (size_t)1536 * 1681 + 1681 + 64){
        nblk = 1536; pG = ws + PERS; G = pG + (size_t)nblk * 1681;
    } else if (ws_f >= PERS + (size_t)768 * 1681 + 1681 + 64){
        nblk = 768;  pG = ws + PERS; G = pG + (size_t)nblk * 1681;
    } else if (ws_f >= PERS + (size_t)384 * 1681 + 1681 + 64){
        nblk = 384;  pG = ws + PERS; G = pG + (size_t)nblk * 1681;
    } else {
        // compact overlay: pG over fea..SRL (dead until k_embed); G inside ST
        // (written by k_pre AFTER k_quad consumed G).
        nblk = 384;  pG = ws;        G = ws + 650000;
    }
    int rpb = 1536 / nblk;
    int ph  = nblk / 96;

    hipMemsetAsync(G, 0, Kc * Kc * sizeof(float), stream);
    k_gram <<<nblk, 128, 0, stream>>>(nbr, pG, rpb);
    k_gred <<<27 * ph, 64, 0, stream>>>(pG, G);
    k_wt   <<<NCc, C2, 0, stream>>>(convW, W3T);
    k_wtb  <<<NCc, 256, 0, stream>>>(convW, W3F);
    k_quad <<<NCc, C2, 0, stream>>>(G, convW, q3);
    k_embed<<<ROWS / 4, 256, 0, stream>>>(atom, embW, embB, fea);
    k_pre  <<<ROWS, 256, 0, stream>>>(nbr, adj, ST, cntf);
    hipMemsetAsync(SRL, 0, 3 * SRL_STRIDE * sizeof(float), stream);

    for (int l = 0; l < NCc; ++l){
        const float* Wl   = convW + (size_t)l * 169 * C2;
        const float* bl   = convB + l * C2;
        const float* W3Tl = W3T + (size_t)l * C2 * 44;
        const unsigned short* W3Fl = W3F + (size_t)l * WFRAG;
        float* sum1R = SRL + l * SRL_STRIDE;
        float* sq1R  = sum1R + 4096;
        float* sum2R = sum1R + 8192;
        float* sq2R  = sum1R + 10240;
        const float* sum2Rp = (l > 0) ? SRL + (l - 1) * SRL_STRIDE + 8192 : SRL;
        const float* sq2Rp  = (l > 0) ? SRL + (l - 1) * SRL_STRIDE + 10240 : SRL;
        const float* g2p    = bn2g + (l > 0 ? (l - 1) : 0) * Fc;
        const float* b2p    = bn2b + (l > 0 ? (l - 1) : 0) * Fc;

        k_front <<<ROWS, 256, 0, stream>>>(fea, Wl, bl, W3Tl, ST, cntf,
                                           p1, p2, sum1R, sq1R,
                                           summed, sum2Rp, sq2Rp, g2p, b2p,
                                           l > 0 ? 1 : 0);
        k_apply <<<ROWS, 512, 0, stream>>>(nbr, adj, W3Fl, p1, p2,
                                           sum1R, sq1R, q3 + l * C2,
                                           bn1g + l * C2, bn1b + l * C2,
                                           summed, sum2R, sq2R);
    }

    k_final<<<N0c, Hc, 0, stream>>>(fea, summed,
                                    SRL + 2 * SRL_STRIDE + 8192,
                                    SRL + 2 * SRL_STRIDE + 10240,
                                    bn2g + 2 * Fc, bn2b + 2 * Fc,
                                    fcW, fcb, outW, outb, out);
}

// Round 16
// 287.410 us; speedup vs baseline: 1.0579x; 1.0230x over previous
//
#include <hip/hip_runtime.h>
#include <math.h>

#define N0c   16
#define NAt   96
#define ORIG  92
#define Fc    64
#define Kc    41
#define Hc    128
#define NCc   3
#define C2    128   // 2F
#define EPSBN 1e-5f
#define JG    4
#define JPW   (NAt / JG)
#define NREP  32    // atomic replica slots
#define SRL_STRIDE 12288   // per-layer replica block
#define AROW  72    // k_apply LDS A row stride (ushorts)
#define WFRAG 16384 // ushorts per layer in W3F (k_apply B frags)
#define INV1  (1.f / (float)(N0c * NAt * NAt))
#define INV2  (1.f / (float)(N0c * NAt))

typedef __attribute__((ext_vector_type(8))) short short8_t;   // 8 bf16
typedef __attribute__((ext_vector_type(4))) float f32x4;

__device__ __forceinline__ float sp_(float x){
    return fmaxf(x, 0.f) + __logf(1.f + __expf(-fabsf(x)));
}
__device__ __forceinline__ float sgm_(float x){
    return 1.f / (1.f + __expf(-x));
}
__device__ __forceinline__ unsigned short bfhi(float x){
    union { float f; unsigned u; } v; v.f = x;
    unsigned r = v.u + 0x7fff + ((v.u >> 16) & 1);   // RNE to bf16
    return (unsigned short)(r >> 16);
}
__device__ __forceinline__ float bf2f(unsigned short h){
    union { float f; unsigned u; } v; v.u = ((unsigned)h) << 16; return v.f;
}

// Compact-ws fallback only: S_r, T_r, cnt_r (identical to R15 k_pre).
__global__ __launch_bounds__(256) void k_pre(const float* __restrict__ nbr,
                                             const int*   __restrict__ adj,
                                             float* __restrict__ ST,
                                             float* __restrict__ cntf){
    int r    = blockIdx.x;
    int lane = threadIdx.x & 63;
    int jg   = __builtin_amdgcn_readfirstlane(threadIdx.x >> 6);
    __shared__ float rS[JG][Kc], rT[JG][Kc], rc[JG];
    float S = 0.f, T = 0.f, cn = 0.f;
    int j0 = jg * JPW;
    for (int j = j0; j < j0 + JPW; ++j){
        float a = (float)adj[r * NAt + j];
        float v = (lane < Kc) ? nbr[((size_t)r * NAt + j) * Kc + lane] : 0.f;
        S += v; T += a * v; cn += a;
    }
    if (lane < Kc){ rS[jg][lane] = S; rT[jg][lane] = T; }
    if (lane == 0) rc[jg] = cn;
    __syncthreads();
    int t = threadIdx.x;
    if (t < Kc){
        ST[r * (2 * Kc) + t]      = rS[0][t] + rS[1][t] + rS[2][t] + rS[3][t];
        ST[r * (2 * Kc) + Kc + t] = rT[0][t] + rT[1][t] + rT[2][t] + rT[3][t];
    }
    if (t == 0) cntf[r] = rc[0] + rc[1] + rc[2] + rc[3];
}

// Gram partials + (fused) S/T/cnt + G-zeroing. Gram inner loop identical to
// R13 (verified). doST=1: block also emits ST/cntf for its rows from the
// already-staged LDS tile (kills the separate k_pre dispatch + 24MB re-read).
__global__ __launch_bounds__(128) void k_gram(const float* __restrict__ nbr,
                                              const int*   __restrict__ adj,
                                              float* __restrict__ pG,
                                              float* __restrict__ ST,
                                              float* __restrict__ cntf,
                                              float* __restrict__ G,
                                              int rpb, int doST){
    int blk = blockIdx.x;
    int t   = threadIdx.x;
    int k   = (t % 21) * 2;
    int lb  = (t / 21) * 7;
    __shared__ float L[NAt * Kc];
    __shared__ float AJf[NAt];
    if (blk == 0){                                   // zero G (consumed by gred)
        for (int i = t; i < Kc * Kc; i += 128) G[i] = 0.f;
    }
    float a0[7] = {0,0,0,0,0,0,0}, a1[7] = {0,0,0,0,0,0,0};
    for (int rr = 0; rr < rpb; ++rr){
        int r = blk * rpb + rr;
        __syncthreads();
        for (int i = t; i < NAt * Kc; i += 128)
            L[i] = nbr[(size_t)r * NAt * Kc + i];
        if (t < NAt) AJf[t] = (float)adj[r * NAt + t];
        __syncthreads();
        if (doST && t < Kc){                         // S/T from LDS tile
            float S = 0.f, T = 0.f;
            for (int j = 0; j < NAt; ++j){
                float v = L[j * Kc + t];
                S += v; T += AJf[j] * v;
            }
            ST[r * (2 * Kc) + t]      = S;
            ST[r * (2 * Kc) + Kc + t] = T;
        }
        if (doST && t == Kc){
            float cn = 0.f;
            for (int j = 0; j < NAt; ++j) cn += AJf[j];
            cntf[r] = cn;
        }
        if (t < 126){
            for (int j = 0; j < NAt; ++j){
                float vk0 = L[j * Kc + k];
                float vk1 = (k + 1 < Kc) ? L[j * Kc + k + 1] : 0.f;
                #pragma unroll
                for (int m = 0; m < 7; ++m){
                    if (lb + m < Kc){
                        float lv = L[j * Kc + lb + m];
                        a0[m] += vk0 * lv;
                        a1[m] += vk1 * lv;
                    }
                }
            }
        }
    }
    if (t < 126){
        float* dst = pG + (size_t)blk * (Kc * Kc);
        #pragma unroll
        for (int m = 0; m < 7; ++m){
            if (lb + m < Kc){
                dst[k * Kc + lb + m] = a0[m];
                if (k + 1 < Kc) dst[(k + 1) * Kc + lb + m] = a1[m];
            }
        }
    }
}

__global__ __launch_bounds__(64) void k_gred(const float* __restrict__ pG,
                                             float* __restrict__ G){
    int i  = (blockIdx.x % 27) * 64 + threadIdx.x;
    int b0 = (blockIdx.x / 27) * 96;
    if (i < Kc * Kc){
        float s = 0.f;
        #pragma unroll 4
        for (int b = b0; b < b0 + 96; ++b) s += pG[(size_t)b * (Kc * Kc) + i];
        atomicAdd(&G[i], s);
    }
}

// One-time prep, fused: W3T (k_front float weights) + W3F (k_apply bf16
// hi/lo B-fragments, R13-verified layout) + q3 = w3^T G w3. Block = layer.
__global__ __launch_bounds__(256) void k_prep(const float* __restrict__ G,
                                              const float* __restrict__ convW,
                                              float* __restrict__ W3T,
                                              unsigned short* __restrict__ W3F,
                                              float* __restrict__ q3){
    int l   = blockIdx.x;
    int tid = threadIdx.x;
    const float* Wl = convW + (size_t)l * 169 * C2;
    __shared__ float GL[Kc * Kc];
    for (int i = tid; i < Kc * Kc; i += 256) GL[i] = G[i];
    __syncthreads();
    // (a) W3F fragments (identical math to R13 k_wtb)
    for (int it = 0; it < 8; ++it){
        int idx  = tid + it * 256;
        int lane = idx & 63;
        int fid  = idx >> 6;
        int h    = fid & 1;
        int ks   = (fid >> 1) & 1;
        int nt   = fid >> 2;
        int n    = nt * 16 + (lane & 15);
        unsigned short* dst = W3F + (size_t)l * WFRAG + fid * 512 + lane * 8;
        #pragma unroll
        for (int i = 0; i < 8; ++i){
            int kk = ks * 32 + (lane >> 4) * 8 + i;
            float w = (kk < Kc) ? Wl[(C2 + kk) * C2 + n] : 0.f;
            unsigned short hi = bfhi(w);
            dst[i] = h ? bfhi(w - bf2f(hi)) : hi;
        }
    }
    // (b) W3T + (c) q3 for channels 0..127
    if (tid < C2){
        int c = tid;
        float* dstT = W3T + ((size_t)l * C2 + c) * 44;
        float w3[Kc];
        #pragma unroll
        for (int kk = 0; kk < Kc; ++kk){
            w3[kk] = Wl[(C2 + kk) * C2 + c];
            dstT[kk] = w3[kk];
        }
        dstT[41] = 0.f; dstT[42] = 0.f; dstT[43] = 0.f;
        float q = 0.f;
        for (int kk = 0; kk < Kc; ++kk){
            float gw = 0.f;
            #pragma unroll
            for (int m = 0; m < Kc; ++m) gw += GL[kk * Kc + m] * w3[m];
            q += w3[kk] * gw;
        }
        q3[l * C2 + c] = q;
    }
}

// Front (R15 v3 structure) + embed fold: at l==0 (upd==0) threads compute
// fea = atom @ emb_W + emb_b inline instead of reading a pre-built fea.
__global__ __launch_bounds__(256)
void k_front(float* __restrict__ fea,
             const float* __restrict__ atom,
             const float* __restrict__ embW,
             const float* __restrict__ embB,
             const float* __restrict__ Wl,
             const float* __restrict__ bl,
             const float* __restrict__ W3Tl,
             const float* __restrict__ ST,
             const float* __restrict__ cntf,
             float* __restrict__ p1,
             float* __restrict__ p2,
             float* __restrict__ sum1R,
             float* __restrict__ sq1R,
             const float* __restrict__ summed,
             const float* __restrict__ sum2Rp,
             const float* __restrict__ sq2Rp,
             const float* __restrict__ g2p,
             const float* __restrict__ b2p,
             int upd){
    int r    = blockIdx.x;
    int tid  = threadIdx.x;
    int c    = tid & 127;
    int half = __builtin_amdgcn_readfirstlane(tid >> 7);
    __shared__ float F[Fc];
    __shared__ float A2L[Fc], B2L[Fc];
    __shared__ float P1h[C2], P2h[C2], TTs[C2];

    if (upd){
        if (tid < Fc){
            float s = 0.f, q = 0.f;
            for (int rr = 0; rr < NREP; ++rr){
                s += sum2Rp[rr * Fc + tid];
                q += sq2Rp[rr * Fc + tid];
            }
            float m = s * INV2;
            float v = q * INV2 - m * m;
            float A = g2p[tid] * rsqrtf(v + EPSBN);
            A2L[tid] = A;
            B2L[tid] = b2p[tid] - m * A;
        }
        __syncthreads();
        if (tid < Fc){
            float nv = sp_(fea[r * Fc + tid] + summed[r * Fc + tid] * A2L[tid] + B2L[tid]);
            F[tid] = nv;
            fea[r * Fc + tid] = nv;          // persist for next front / k_final
        }
        __syncthreads();
    } else {
        // l==0: embed inline (atom row is wave-uniform -> s_loads)
        if (tid < Fc){
            const float* ar = atom + r * ORIG;
            float acc = embB[tid];
            #pragma unroll 4
            for (int o = 0; o < ORIG; ++o) acc += ar[o] * embW[o * Fc + tid];
            F[tid] = acc;
            fea[r * Fc + tid] = acc;         // consumed by front l=1
        }
        __syncthreads();
    }

    // p12 partial over f in [half*32, half*32+32)
    float a1p = 0.f, a2p = 0.f;
    int f0 = half * 32;
    #pragma unroll 8
    for (int f = f0; f < f0 + 32; ++f){
        float fv = F[f];                     // LDS broadcast
        a1p += fv * Wl[f * C2 + c];
        a2p += fv * Wl[(Fc + f) * C2 + c];
    }
    // dot: half 0 -> u = S·w3 ; half 1 -> tt = T·w3 (uniform s_loads of S/T)
    const float* wt = W3Tl + c * 44;
    const float* Sr = ST + r * (2 * Kc) + half * Kc;
    float dot = 0.f;
    #pragma unroll
    for (int k = 0; k < 40; k += 4){
        float4 wv = *(const float4*)(wt + k);
        dot += Sr[k] * wv.x + Sr[k + 1] * wv.y + Sr[k + 2] * wv.z + Sr[k + 3] * wv.w;
    }
    dot += Sr[40] * wt[40];

    if (half == 1){ P1h[c] = a1p; P2h[c] = a2p; TTs[c] = dot; }
    __syncthreads();
    if (half == 0){
        float a1 = a1p + P1h[c] + bl[c];
        float a2 = a2p + P2h[c];
        float u  = dot;
        float tt = TTs[c];
        p1[r * C2 + c] = a1;
        p2[r * C2 + c] = a2;
        float cn = cntf[r];
        float s1 = (float)NAt * a1 + cn * a2 + u;
        float q1 = (float)NAt * a1 * a1 + cn * a2 * a2
                 + 2.f * cn * a1 * a2 + 2.f * a1 * u + 2.f * a2 * tt;
        int slot = blockIdx.x & (NREP - 1);
        atomicAdd(&sum1R[slot * C2 + c], s1);
        atomicAdd(&sq1R[slot * C2 + c], q1);
    }
}

// Pass 2 (MFMA, identical to R13 — verified, ~35 us).
__global__ __launch_bounds__(512)
void k_apply(const float* __restrict__ nbr,
             const int*   __restrict__ adj,
             const unsigned short* __restrict__ W3Fl,
             const float* __restrict__ p1,
             const float* __restrict__ p2,
             const float* __restrict__ sum1R,
             const float* __restrict__ sq1R,
             const float* __restrict__ qv,
             const float* __restrict__ g1,
             const float* __restrict__ b1,
             float* __restrict__ summed,
             float* __restrict__ sum2R,
             float* __restrict__ sq2R){
    int r    = blockIdx.x;
    int tid  = threadIdx.x;
    int lane = tid & 63;
    int w    = __builtin_amdgcn_readfirstlane(tid >> 6);
    int ntF  = w & 3;
    int mh   = w >> 2;

    __shared__ unsigned short sAH[NAt * AROW];
    __shared__ unsigned short sAL[NAt * AROW];
    __shared__ float AJ[NAt];
    __shared__ float PL1[C2], PL2[C2], A1L[C2], B1L[C2];
    __shared__ float TpW[8][16];

    short8_t BH[2][2], BL[2][2];
    #pragma unroll
    for (int ni = 0; ni < 2; ++ni){
        int nt = ntF + ni * 4;
        #pragma unroll
        for (int ks = 0; ks < 2; ++ks){
            int fidH = (nt * 2 + ks) * 2;
            BH[ni][ks] = *(const short8_t*)(W3Fl + fidH * 512 + lane * 8);
            BL[ni][ks] = *(const short8_t*)(W3Fl + (fidH + 1) * 512 + lane * 8);
        }
    }

    const float* nb = nbr + (size_t)r * (NAt * Kc);
    for (int idx = tid; idx < NAt * Kc; idx += 512){
        int j = idx / Kc, k = idx - j * Kc;
        float x = nb[idx];
        unsigned short hi = bfhi(x);
        sAH[j * AROW + k] = hi;
        sAL[j * AROW + k] = bfhi(x - bf2f(hi));
    }
    for (int idx = tid; idx < NAt * 23; idx += 512){
        int j = idx / 23, k = Kc + (idx - j * 23);
        sAH[j * AROW + k] = 0;
        sAL[j * AROW + k] = 0;
    }
    if (tid < C2){
        int c = tid;
        float s = 0.f, q = 0.f;
        for (int rr = 0; rr < NREP; ++rr){ s += sum1R[rr * C2 + c]; q += sq1R[rr * C2 + c]; }
        float m = s * INV1;
        float v = (q + qv[c]) * INV1 - m * m;
        float A = g1[c] * rsqrtf(v + EPSBN);
        A1L[c] = A;
        B1L[c] = b1[c] - m * A;
    } else if (tid < 256){
        PL1[tid - 128] = p1[r * C2 + tid - 128];
    } else if (tid < 384){
        PL2[tid - 256] = p2[r * C2 + tid - 256];
    } else if (tid < 480){
        AJ[tid - 384] = (float)adj[r * NAt + tid - 384];
    }
    __syncthreads();

    f32x4 acc[3][2] = {};
    int q4 = (lane >> 4) * 8;
    #pragma unroll
    for (int mt = 0; mt < 3; ++mt){
        int jrow = (mh * 48 + mt * 16 + (lane & 15)) * AROW;
        short8_t AH0 = *(const short8_t*)(&sAH[jrow + q4]);
        short8_t AH1 = *(const short8_t*)(&sAH[jrow + 32 + q4]);
        short8_t AL0 = *(const short8_t*)(&sAL[jrow + q4]);
        short8_t AL1 = *(const short8_t*)(&sAL[jrow + 32 + q4]);
        #pragma unroll
        for (int ni = 0; ni < 2; ++ni){
            acc[mt][ni] = __builtin_amdgcn_mfma_f32_16x16x32_bf16(AH0, BH[ni][0], acc[mt][ni], 0, 0, 0);
            acc[mt][ni] = __builtin_amdgcn_mfma_f32_16x16x32_bf16(AH0, BL[ni][0], acc[mt][ni], 0, 0, 0);
            acc[mt][ni] = __builtin_amdgcn_mfma_f32_16x16x32_bf16(AL0, BH[ni][0], acc[mt][ni], 0, 0, 0);
            acc[mt][ni] = __builtin_amdgcn_mfma_f32_16x16x32_bf16(AH1, BH[ni][1], acc[mt][ni], 0, 0, 0);
            acc[mt][ni] = __builtin_amdgcn_mfma_f32_16x16x32_bf16(AH1, BL[ni][1], acc[mt][ni], 0, 0, 0);
            acc[mt][ni] = __builtin_amdgcn_mfma_f32_16x16x32_bf16(AL1, BH[ni][1], acc[mt][ni], 0, 0, 0);
        }
    }

    int cF = ntF * 16 + (lane & 15);
    int cC = cF + 64;
    float p1F = PL1[cF], p2F = PL2[cF], A1F = A1L[cF], B1F = B1L[cF];
    float p1C = PL1[cC], p2C = PL2[cC], A1C = A1L[cC], B1C = B1L[cC];
    float tsum = 0.f;
    #pragma unroll
    for (int mt = 0; mt < 3; ++mt){
        #pragma unroll
        for (int rg = 0; rg < 4; ++rg){
            int j = mh * 48 + mt * 16 + (lane >> 4) * 4 + rg;
            float ajf = AJ[j];
            float gf = (p1F + ajf * p2F + acc[mt][0][rg]) * A1F + B1F;
            float gc = (p1C + ajf * p2C + acc[mt][1][rg]) * A1C + B1C;
            tsum += sgm_(gf) * sp_(gc);
        }
    }
    tsum += __shfl_xor(tsum, 16);
    tsum += __shfl_xor(tsum, 32);
    if (lane < 16) TpW[w][lane] = tsum;
    __syncthreads();
    if (tid < Fc){
        int f = tid;
        float s = TpW[f >> 4][f & 15] + TpW[(f >> 4) + 4][f & 15];
        summed[r * Fc + f] = s;
        int slot = blockIdx.x & (NREP - 1);
        atomicAdd(&sum2R[slot * Fc + f], s);
        atomicAdd(&sq2R[slot * Fc + f], s * s);
    }
}

// Tail (identical to R13).
__global__ __launch_bounds__(128) void k_final(const float* __restrict__ fea,
                                               const float* __restrict__ summed,
                                               const float* __restrict__ sum2R,
                                               const float* __restrict__ sq2R,
                                               const float* __restrict__ g2,
                                               const float* __restrict__ b2,
                                               const float* __restrict__ fcW,
                                               const float* __restrict__ fcb,
                                               const float* __restrict__ outW,
                                               const float* __restrict__ outb,
                                               float* __restrict__ out){
    int b = blockIdx.x;
    int t = threadIdx.x;
    __shared__ float spc[Fc];
    __shared__ float red[Hc];
    if (t < Fc){
        float s = 0.f, q = 0.f;
        for (int r = 0; r < NREP; ++r){ s += sum2R[r * Fc + t]; q += sq2R[r * Fc + t]; }
        float m  = s * INV2;
        float v  = q * INV2 - m * m;
        float A2 = g2[t] * rsqrtf(v + EPSBN);
        float B2 = b2[t] - m * A2;
        float acc = 0.f;
        for (int i = 0; i < NAt; ++i){
            int idx = (b * NAt + i) * Fc + t;
            acc += sp_(fea[idx] + summed[idx] * A2 + B2);
        }
        spc[t] = sp_(acc * (1.f / NAt));
    }
    __syncthreads();
    float h = fcb[t];
    #pragma unroll 4
    for (int f = 0; f < Fc; ++f) h += spc[f] * fcW[f * Hc + t];
    h = sp_(h);
    red[t] = h * outW[t];
    __syncthreads();
    for (int off = 64; off > 0; off >>= 1){
        if (t < off) red[t] += red[t + off];
        __syncthreads();
    }
    if (t == 0) out[b] = red[0] + outb[0];
}

extern "C" void kernel_launch(void* const* d_in, const int* in_sizes, int n_in,
                              void* d_out, int out_size, void* d_ws, size_t ws_size,
                              hipStream_t stream){
    const float* atom  = (const float*)d_in[0];
    const float* nbr   = (const float*)d_in[1];
    const int*   adj   = (const int*)  d_in[2];
    const float* embW  = (const float*)d_in[3];
    const float* embB  = (const float*)d_in[4];
    const float* convW = (const float*)d_in[5];
    const float* convB = (const float*)d_in[6];
    const float* bn1g  = (const float*)d_in[7];
    const float* bn1b  = (const float*)d_in[8];
    const float* bn2g  = (const float*)d_in[9];
    const float* bn2b  = (const float*)d_in[10];
    const float* fcW   = (const float*)d_in[11];
    const float* fcb   = (const float*)d_in[12];
    const float* outW  = (const float*)d_in[13];
    const float* outb  = (const float*)d_in[14];
    float* out = (float*)d_out;
    float* ws  = (float*)d_ws;

    const int ROWS = N0c * NAt;            // 1536
    float* fea    = ws;                    // 98304
    float* p1     = ws + 98304;            // 196608
    float* p2     = ws + 294912;           // 196608
    float* summed = ws + 491520;           // 98304
    float* SRL    = ws + 589824;           // 3 * 12288
    float* ST     = ws + 626688;           // 125952
    float* cntf   = ws + 752640;           // 1536
    float* q3     = ws + 754176;           // 384
    float* W3T    = ws + 754560;           // 16896
    unsigned short* W3F = (unsigned short*)(ws + 771456);  // 24576 f
    const size_t PERS = 796032;

    size_t ws_f = ws_size / sizeof(float);
    int nblk; float *pG, *G; int compact = 0;
    if (ws_f >= PERS + (size_t)1536 * 1681 + 1681 + 64){
        nblk = 1536; pG = ws + PERS; G = pG + (size_t)nblk * 1681;
    } else if (ws_f >= PERS + (size_t)768 * 1681 + 1681 + 64){
        nblk = 768;  pG = ws + PERS; G = pG + (size_t)nblk * 1681;
    } else if (ws_f >= PERS + (size_t)384 * 1681 + 1681 + 64){
        nblk = 384;  pG = ws + PERS; G = pG + (size_t)nblk * 1681;
    } else {
        // compact overlay: pG over fea..SRL (dead until front l0); G inside
        // ST region — so ST must come from the separate k_pre AFTER k_prep
        // consumed G. Gram runs with doST=0 in this tier.
        nblk = 384;  pG = ws;        G = ws + 650000;  compact = 1;
    }
    int rpb = 1536 / nblk;
    int ph  = nblk / 96;

    // 1: gram (+ST/cnt fused unless compact; zeroes G from block 0)
    k_gram <<<nblk, 128, 0, stream>>>(nbr, adj, pG, ST, cntf, G, rpb,
                                      compact ? 0 : 1);
    // 2: reduce gram partials into G
    k_gred <<<27 * ph, 64, 0, stream>>>(pG, G);
    // 3: one-time weight prep (W3T + W3F + q3)
    k_prep <<<NCc, 256, 0, stream>>>(G, convW, W3T, W3F, q3);
    // 3b (compact tier only): ST/cnt via standalone pre (after G consumed)
    if (compact)
        k_pre <<<ROWS, 256, 0, stream>>>(nbr, adj, ST, cntf);
    // 4: zero all replica stats once
    hipMemsetAsync(SRL, 0, 3 * SRL_STRIDE * sizeof(float), stream);

    for (int l = 0; l < NCc; ++l){
        const float* Wl   = convW + (size_t)l * 169 * C2;
        const float* bl   = convB + l * C2;
        const float* W3Tl = W3T + (size_t)l * C2 * 44;
        const unsigned short* W3Fl = W3F + (size_t)l * WFRAG;
        float* sum1R = SRL + l * SRL_STRIDE;
        float* sq1R  = sum1R + 4096;
        float* sum2R = sum1R + 8192;
        float* sq2R  = sum1R + 10240;
        const float* sum2Rp = (l > 0) ? SRL + (l - 1) * SRL_STRIDE + 8192 : SRL;
        const float* sq2Rp  = (l > 0) ? SRL + (l - 1) * SRL_STRIDE + 10240 : SRL;
        const float* g2p    = bn2g + (l > 0 ? (l - 1) : 0) * Fc;
        const float* b2p    = bn2b + (l > 0 ? (l - 1) : 0) * Fc;

        k_front <<<ROWS, 256, 0, stream>>>(fea, atom, embW, embB,
                                           Wl, bl, W3Tl, ST, cntf,
                                           p1, p2, sum1R, sq1R,
                                           summed, sum2Rp, sq2Rp, g2p, b2p,
                                           l > 0 ? 1 : 0);
        k_apply <<<ROWS, 512, 0, stream>>>(nbr, adj, W3Fl, p1, p2,
                                           sum1R, sq1R, q3 + l * C2,
                                           bn1g + l * C2, bn1b + l * C2,
                                           summed, sum2R, sq2R);
    }

    k_final<<<N0c, Hc, 0, stream>>>(fea, summed,
                                    SRL + 2 * SRL_STRIDE + 8192,
                                    SRL + 2 * SRL_STRIDE + 10240,
                                    bn2g + 2 * Fc, bn2b + 2 * Fc,
                                    fcW, fcb, outW, outb, out);
}